// Round 1
// baseline (224.348 us; speedup 1.0000x reference)
//
#include <hip/hip_runtime.h>
#include <hip/hip_fp16.h>

// DPLSafePolicy: logits = x @ [Wg|Wp|Wa] (16384x2048 @ 2048x13), then
// softmax(g),softmax(p),softmax(a); unsafe from closed-form sparse T;
// out = a*(1-unsafe) renormalized. HBM-bound on reading x (134 MB).
//
// Layout: block=256 (4 waves), grid=B/32. Each wave owns 8 rows over full H.
// Lane l -> (row = l&7, phase = l>>3). Per 32-h chunk, the wave stages
// x[8 rows x 32 h] (one float4/lane, coalesced 128B segments) into a
// per-wave double-buffered LDS tile (row stride 9 float4 = 36 dwords ->
// conflict-free b128 in 8-lane granules). Weight reads are phase-uniform
// -> LDS broadcasts. Accumulators are per-lane partials over phase's h
// subset; 3 shfl_xor butterflies (masks 8,16,32) finish all 8 rows' 13
// logits in 39 shuffles. Weights in LDS as fp16 (52 KB -> 61 KB/block ->
// 2 blocks/CU = 8 waves/CU); fp32 x and fp32 accumulate keep absmax ~1e-3
// vs threshold 1.9e-2.

__global__ __launch_bounds__(256, 2)
void dpl_safe_policy_kernel(const float* __restrict__ x,
                            const float* __restrict__ Wg, const float* __restrict__ bg,
                            const float* __restrict__ Wp, const float* __restrict__ bp,
                            const float* __restrict__ Wa, const float* __restrict__ ba,
                            float* __restrict__ out)
{
    __shared__ __half wlds[13 * 2048];   // 52 KB, [j][h]
    __shared__ float4 xt[4][2][72];      // per-wave dbuf tile: [wave][buf][row*9+pos], 9 KB

    const int tid = threadIdx.x;

    // ---- stage weights (transpose to j-major, fp16), one-time ----
    for (int idx = tid; idx < 13 * 2048; idx += 256) {
        const int j = idx >> 11, h = idx & 2047;
        float v;
        if (j < 4)      v = Wg[h * 4 + j];
        else if (j < 8) v = Wp[h * 4 + (j - 4)];
        else            v = Wa[h * 5 + (j - 8)];
        wlds[idx] = __float2half(v);
    }
    __syncthreads();

    const int w  = tid >> 6;     // wave 0..3
    const int l  = tid & 63;
    const int r8 = l & 7;        // compute: row-in-group ; staging: f4 pos
    const int p  = l >> 3;       // compute: phase (0..7) ; staging: row-in-group
    const int rowbase = blockIdx.x * 32 + w * 8;

    const float4* xg = (const float4*)x;
    const long gbase = (long)(rowbase + p) * 512 + r8;   // staging f4 address

    float4* tw = &xt[w][0][0];
    const int wr_off = p * 9 + r8;   // staging write slot
    const int rd_off = r8 * 9 + p;   // compute read slot

    // ---- prefetch pipeline: LDS holds chunk0; regs hold chunks 1..3 ----
    float4 x0 = xg[gbase];
    tw[wr_off] = x0;
    float4 xn0 = xg[gbase + 8];
    float4 xn1 = xg[gbase + 16];
    float4 xn2 = xg[gbase + 24];

    float acc[13];
    #pragma unroll
    for (int j = 0; j < 13; ++j) acc[j] = 0.f;

    const __half2* w2 = (const __half2*)wlds;

    #pragma unroll 4
    for (int c = 0; c < 64; ++c) {
        const int buf = c & 1;
        if (c + 1 < 64) tw[(buf ^ 1) * 72 + wr_off] = xn0;   // stage chunk c+1
        xn0 = xn1; xn1 = xn2;
        if (c + 4 < 64) xn2 = xg[gbase + (c + 4) * 8];       // fetch chunk c+4
        const float4 xv = tw[buf * 72 + rd_off];             // read chunk c
        const int wb = c * 16 + p * 2;                       // half2 idx within j-row
        #pragma unroll
        for (int j = 0; j < 13; ++j) {
            const __half2 ha = w2[j * 1024 + wb];
            const __half2 hb = w2[j * 1024 + wb + 1];
            const float2 fa = __half22float2(ha);
            const float2 fb = __half22float2(hb);
            acc[j] += xv.x * fa.x + xv.y * fa.y + xv.z * fb.x + xv.w * fb.y;
        }
    }

    // ---- reduce over phases: lanes differing in bits 3..5 share a row ----
    #pragma unroll
    for (int j = 0; j < 13; ++j) {
        acc[j] += __shfl_xor(acc[j], 8,  64);
        acc[j] += __shfl_xor(acc[j], 16, 64);
        acc[j] += __shfl_xor(acc[j], 32, 64);
    }

    // ---- epilogue: softmaxes + sparse-T safety combine (all fp32) ----
    const float g0 = acc[0] + bg[0], g1 = acc[1] + bg[1], g2 = acc[2] + bg[2], g3 = acc[3] + bg[3];
    const float q0 = acc[4] + bp[0], q1 = acc[5] + bp[1], q2 = acc[6] + bp[2], q3 = acc[7] + bp[3];
    const float a0 = acc[8] + ba[0], a1 = acc[9] + ba[1], a2 = acc[10] + ba[2],
                a3 = acc[11] + ba[3], a4 = acc[12] + ba[4];

    float m, s, inv;
    m = fmaxf(fmaxf(g0, g1), fmaxf(g2, g3));
    const float eg0 = __expf(g0 - m), eg1 = __expf(g1 - m), eg2 = __expf(g2 - m), eg3 = __expf(g3 - m);
    s = eg0 + eg1 + eg2 + eg3; inv = 1.f / s;
    const float G0 = eg0 * inv, G1 = eg1 * inv, G2 = eg2 * inv, G3 = eg3 * inv;

    m = fmaxf(fmaxf(q0, q1), fmaxf(q2, q3));
    const float ep0 = __expf(q0 - m), ep1 = __expf(q1 - m), ep2 = __expf(q2 - m), ep3 = __expf(q3 - m);
    s = ep0 + ep1 + ep2 + ep3; inv = 1.f / s;
    const float P0 = ep0 * inv, P1 = ep1 * inv, P2 = ep2 * inv, P3 = ep3 * inv;

    m = fmaxf(fmaxf(fmaxf(a0, a1), fmaxf(a2, a3)), a4);
    const float ea0 = __expf(a0 - m), ea1 = __expf(a1 - m), ea2 = __expf(a2 - m),
                ea3 = __expf(a3 - m), ea4 = __expf(a4 - m);
    s = ea0 + ea1 + ea2 + ea3 + ea4; inv = 1.f / s;
    const float A0 = ea0 * inv, A1 = ea1 * inv, A2 = ea2 * inv, A3 = ea3 * inv, A4 = ea4 * inv;

    const float u0 = P0 * G0 + P1 * G1 + P2 * G2 + P3 * G3;  // stay
    const float u1 = P0 * G1 + P2 * G3;                      // up
    const float u2 = P1 * G0 + P3 * G2;                      // down

    const float j0 = A0 * (1.f - u0), j1 = A1 * (1.f - u1), j2 = A2 * (1.f - u2),
                j3 = A3, j4 = A4;
    const float isd = 1.f / (j0 + j1 + j2 + j3 + j4);

    const int row = rowbase + r8;
    const float ov = (p == 0) ? j0 : (p == 1) ? j1 : (p == 2) ? j2 : (p == 3) ? j3 : j4;
    if (p < 5) out[row * 5 + p] = ov * isd;
}

extern "C" void kernel_launch(void* const* d_in, const int* in_sizes, int n_in,
                              void* d_out, int out_size, void* d_ws, size_t ws_size,
                              hipStream_t stream) {
    const float* x  = (const float*)d_in[0];
    const float* Wg = (const float*)d_in[1];
    const float* bg = (const float*)d_in[2];
    const float* Wp = (const float*)d_in[3];
    const float* bp = (const float*)d_in[4];
    const float* Wa = (const float*)d_in[5];
    const float* ba = (const float*)d_in[6];
    float* out = (float*)d_out;

    const int B = in_sizes[0] / 2048;   // 16384
    const int grid = B / 32;            // 512 blocks, 2/CU
    dpl_safe_policy_kernel<<<grid, 256, 0, stream>>>(x, Wg, bg, Wp, bp, Wa, ba, out);
}

// Round 3
// 210.218 us; speedup vs baseline: 1.0672x; 1.0672x over previous
//
#include <hip/hip_runtime.h>
#include <hip/hip_fp16.h>

// DPLSafePolicy: logits[16384,13] = x[16384,2048] @ [Wg|Wp|Wa], three softmaxes,
// closed-form sparse-T unsafe combine, renormalize -> out[16384,5].
//
// R3 = R2 with __fp16 vector types (cvt_pkrtz / fdot2 take __fp16, not _Float16).
// Design: no x transpose. Lane l of a wave: hs=l&15 (h-quad slot), rg=l>>4
// (row pair). Lane accumulates 2 rows directly from coalesced float4 loads;
// 13 logits finished by shfl_xor masks 1,2,4,8. Weights in LDS fp16 [j][h]
// (52 KB); 13 ds_read_b64/chunk feed 2 rows (weight LDS traffic ~435 MB,
// under HBM floor; 16 unique b64 addrs span 32 banks, 4-lane broadcast ->
// conflict-free). v_dot2_f32_f16 with fp32 accumulate. Block 256, grid 512.

typedef __fp16 h2_t __attribute__((ext_vector_type(2)));
typedef __fp16 h4_t __attribute__((ext_vector_type(4)));

__global__ __launch_bounds__(256, 2)
void dpl_safe_policy_kernel(const float* __restrict__ x,
                            const float* __restrict__ Wg, const float* __restrict__ bg,
                            const float* __restrict__ Wp, const float* __restrict__ bp,
                            const float* __restrict__ Wa, const float* __restrict__ ba,
                            float* __restrict__ out)
{
    __shared__ __align__(16) __fp16 wlds[13 * 2048];   // [j][h], 52 KB

    const int tid = threadIdx.x;

    // ---- stage weights (j-major, fp16) ----
    const float4* Wg4 = (const float4*)Wg;
    const float4* Wp4 = (const float4*)Wp;
    for (int h = tid; h < 2048; h += 256) {
        float4 g = Wg4[h];
        wlds[0 * 2048 + h] = (__fp16)g.x;
        wlds[1 * 2048 + h] = (__fp16)g.y;
        wlds[2 * 2048 + h] = (__fp16)g.z;
        wlds[3 * 2048 + h] = (__fp16)g.w;
        float4 p = Wp4[h];
        wlds[4 * 2048 + h] = (__fp16)p.x;
        wlds[5 * 2048 + h] = (__fp16)p.y;
        wlds[6 * 2048 + h] = (__fp16)p.z;
        wlds[7 * 2048 + h] = (__fp16)p.w;
        #pragma unroll
        for (int j = 0; j < 5; ++j)
            wlds[(8 + j) * 2048 + h] = (__fp16)Wa[h * 5 + j];
    }
    __syncthreads();

    const int w  = tid >> 6;        // wave 0..3
    const int l  = tid & 63;
    const int hs = l & 15;          // h-quad slot 0..15
    const int rg = l >> 4;          // row pair 0..3
    const int rowbase = blockIdx.x * 32 + w * 8;
    const int row0 = rowbase + rg * 2;

    const float4* xg = (const float4*)x;
    const long b0 = (long)row0 * 512 + hs;      // float4 index, row stride 512
    const long b1 = b0 + 512;

    const h4_t* w4 = (const h4_t*)wlds;         // h4 index = j*512 + c*16 + hs

    float acc0[13], acc1[13];
    #pragma unroll
    for (int j = 0; j < 13; ++j) { acc0[j] = 0.f; acc1[j] = 0.f; }

    // prefetch 2 super-iters deep (4 float4 in flight/lane)
    float4 c00 = xg[b0],      c10 = xg[b1];
    float4 c01 = xg[b0 + 16], c11 = xg[b1 + 16];

    #pragma unroll 2
    for (int c = 0; c < 32; ++c) {
        const float4 xv0 = c00, xv1 = c10;
        c00 = c01; c10 = c11;
        if (c + 2 < 32) {
            c01 = xg[b0 + (c + 2) * 16];
            c11 = xg[b1 + (c + 2) * 16];
        }
        const h2_t xl0 = __builtin_amdgcn_cvt_pkrtz(xv0.x, xv0.y);
        const h2_t xh0 = __builtin_amdgcn_cvt_pkrtz(xv0.z, xv0.w);
        const h2_t xl1 = __builtin_amdgcn_cvt_pkrtz(xv1.x, xv1.y);
        const h2_t xh1 = __builtin_amdgcn_cvt_pkrtz(xv1.z, xv1.w);
        const int wb = c * 16 + hs;
        #pragma unroll
        for (int j = 0; j < 13; ++j) {
            const h4_t wv = w4[j * 512 + wb];
            const h2_t wlo = __builtin_shufflevector(wv, wv, 0, 1);
            const h2_t whi = __builtin_shufflevector(wv, wv, 2, 3);
#if __has_builtin(__builtin_amdgcn_fdot2)
            acc0[j] = __builtin_amdgcn_fdot2(xl0, wlo, acc0[j], false);
            acc0[j] = __builtin_amdgcn_fdot2(xh0, whi, acc0[j], false);
            acc1[j] = __builtin_amdgcn_fdot2(xl1, wlo, acc1[j], false);
            acc1[j] = __builtin_amdgcn_fdot2(xh1, whi, acc1[j], false);
#else
            acc0[j] += (float)xl0.x * (float)wlo.x + (float)xl0.y * (float)wlo.y
                     + (float)xh0.x * (float)whi.x + (float)xh0.y * (float)whi.y;
            acc1[j] += (float)xl1.x * (float)wlo.x + (float)xl1.y * (float)wlo.y
                     + (float)xh1.x * (float)whi.x + (float)xh1.y * (float)whi.y;
#endif
        }
    }

    // ---- reduce across the 16 h-slots sharing each row pair ----
    #pragma unroll
    for (int j = 0; j < 13; ++j) {
        acc0[j] += __shfl_xor(acc0[j], 1, 64);
        acc0[j] += __shfl_xor(acc0[j], 2, 64);
        acc0[j] += __shfl_xor(acc0[j], 4, 64);
        acc0[j] += __shfl_xor(acc0[j], 8, 64);
        acc1[j] += __shfl_xor(acc1[j], 1, 64);
        acc1[j] += __shfl_xor(acc1[j], 2, 64);
        acc1[j] += __shfl_xor(acc1[j], 4, 64);
        acc1[j] += __shfl_xor(acc1[j], 8, 64);
    }

    const float vbg0 = bg[0], vbg1 = bg[1], vbg2 = bg[2], vbg3 = bg[3];
    const float vbp0 = bp[0], vbp1 = bp[1], vbp2 = bp[2], vbp3 = bp[3];
    const float vba0 = ba[0], vba1 = ba[1], vba2 = ba[2], vba3 = ba[3], vba4 = ba[4];

    #pragma unroll
    for (int r = 0; r < 2; ++r) {
        const float* acc = r ? acc1 : acc0;
        const float g0 = acc[0] + vbg0, g1 = acc[1] + vbg1, g2 = acc[2] + vbg2, g3 = acc[3] + vbg3;
        const float q0 = acc[4] + vbp0, q1 = acc[5] + vbp1, q2 = acc[6] + vbp2, q3 = acc[7] + vbp3;
        const float a0 = acc[8] + vba0, a1 = acc[9] + vba1, a2 = acc[10] + vba2,
                    a3 = acc[11] + vba3, a4 = acc[12] + vba4;

        float m, s, inv;
        m = fmaxf(fmaxf(g0, g1), fmaxf(g2, g3));
        const float eg0 = __expf(g0 - m), eg1 = __expf(g1 - m), eg2 = __expf(g2 - m), eg3 = __expf(g3 - m);
        s = eg0 + eg1 + eg2 + eg3; inv = 1.f / s;
        const float G0 = eg0 * inv, G1 = eg1 * inv, G2 = eg2 * inv, G3 = eg3 * inv;

        m = fmaxf(fmaxf(q0, q1), fmaxf(q2, q3));
        const float ep0 = __expf(q0 - m), ep1 = __expf(q1 - m), ep2 = __expf(q2 - m), ep3 = __expf(q3 - m);
        s = ep0 + ep1 + ep2 + ep3; inv = 1.f / s;
        const float P0 = ep0 * inv, P1 = ep1 * inv, P2 = ep2 * inv, P3 = ep3 * inv;

        m = fmaxf(fmaxf(fmaxf(a0, a1), fmaxf(a2, a3)), a4);
        const float ea0 = __expf(a0 - m), ea1 = __expf(a1 - m), ea2 = __expf(a2 - m),
                    ea3 = __expf(a3 - m), ea4 = __expf(a4 - m);
        s = ea0 + ea1 + ea2 + ea3 + ea4; inv = 1.f / s;
        const float A0 = ea0 * inv, A1 = ea1 * inv, A2 = ea2 * inv, A3 = ea3 * inv, A4 = ea4 * inv;

        const float u0 = P0 * G0 + P1 * G1 + P2 * G2 + P3 * G3;  // stay
        const float u1 = P0 * G1 + P2 * G3;                      // up
        const float u2 = P1 * G0 + P3 * G2;                      // down

        const float j0 = A0 * (1.f - u0), j1 = A1 * (1.f - u1), j2 = A2 * (1.f - u2),
                    j3 = A3, j4 = A4;
        const float isd = 1.f / (j0 + j1 + j2 + j3 + j4);

        if (hs < 5) {
            const float ov = (hs == 0) ? j0 : (hs == 1) ? j1 : (hs == 2) ? j2 : (hs == 3) ? j3 : j4;
            out[(row0 + r) * 5 + hs] = ov * isd;
        }
    }
}

extern "C" void kernel_launch(void* const* d_in, const int* in_sizes, int n_in,
                              void* d_out, int out_size, void* d_ws, size_t ws_size,
                              hipStream_t stream) {
    const float* x  = (const float*)d_in[0];
    const float* Wg = (const float*)d_in[1];
    const float* bg = (const float*)d_in[2];
    const float* Wp = (const float*)d_in[3];
    const float* bp = (const float*)d_in[4];
    const float* Wa = (const float*)d_in[5];
    const float* ba = (const float*)d_in[6];
    float* out = (float*)d_out;

    const int B = in_sizes[0] / 2048;   // 16384
    const int grid = B / 32;            // 512 blocks
    dpl_safe_policy_kernel<<<grid, 256, 0, stream>>>(x, Wg, bg, Wp, bp, Wa, ba, out);
}

// Round 4
// 206.792 us; speedup vs baseline: 1.0849x; 1.0166x over previous
//
#include <hip/hip_runtime.h>

// DPLSafePolicy: logits[16384,13] = x[16384,2048] @ [Wg|Wp|Wa], 3 softmaxes,
// sparse-T unsafe combine, renormalize -> out[16384,5].
//
// R4: K-split-4 across blocks to break the 8-waves/CU parallelism cap.
//  k1 pack_weights: fp32 -> fp16, layout [s][j][512] in d_ws (53 KB).
//  k2 gemm_partial: grid 2048 (512 row-tiles x 4 K-chunks), block 256.
//     LDS = 13 KB weight chunk only -> ~4 blocks/CU resident (16 waves/CU).
//     Wave = 8 rows: lane (hs=l&15, rg=l>>4) handles rows rg*2+{0,1}; all 16
//     x float4-loads (2 rows x 8 iters) hoisted -> deep MLP. 13 ds_read_b64
//     weight fetches/iter (16 unique addrs, 4-way broadcast, conflict-free)
//     feed 52 v_dot2_f32_f16. shfl_xor(1,2,4,8) finishes logits; lanes
//     hs<13 write fp32 partials [s][row][13] at d_ws+64KB.
//  k3 reduce_epilogue: thread=row, sum 4 partials, biases, softmaxes,
//     combine, write out (20 B/thread, coalesced).

typedef __fp16 h2_t __attribute__((ext_vector_type(2)));
typedef __fp16 h4_t __attribute__((ext_vector_type(4)));

#define WS_PART_OFF 65536   // bytes; fp16 packed weights live at offset 0

__global__ void pack_weights(const float* __restrict__ Wg,
                             const float* __restrict__ Wp,
                             const float* __restrict__ Wa,
                             __fp16* __restrict__ wout)
{
    const int t = blockIdx.x * 256 + threadIdx.x;   // 0..26623 = 13*2048
    const int j = t >> 11, h = t & 2047;
    const int s = h >> 9, hk = h & 511;
    float v;
    if (j < 4)      v = Wg[h * 4 + j];
    else if (j < 8) v = Wp[h * 4 + (j - 4)];
    else            v = Wa[h * 5 + (j - 8)];
    wout[s * 6656 + j * 512 + hk] = (__fp16)v;      // [s][j][hk]
}

__global__ __launch_bounds__(256, 4)
void gemm_partial(const float* __restrict__ x,
                  const __fp16* __restrict__ wpk,
                  float* __restrict__ part)
{
    __shared__ __align__(16) __fp16 wl[13 * 512];   // 13312 B

    const int tid = threadIdx.x;
    const int rt  = blockIdx.x & 511;   // row tile
    const int s   = blockIdx.x >> 9;    // K chunk 0..3

    // stage 13 KB weight chunk: 832 uint4
    {
        const uint4* src = (const uint4*)(wpk + s * 6656);
        uint4* dst = (uint4*)wl;
        int i = tid;
        dst[i] = src[i]; i += 256;
        dst[i] = src[i]; i += 256;
        dst[i] = src[i]; i += 256;
        if (i < 832) dst[i] = src[i];
    }
    __syncthreads();

    const int w  = tid >> 6;
    const int l  = tid & 63;
    const int hs = l & 15;
    const int rg = l >> 4;
    const int row0 = rt * 32 + w * 8 + rg * 2;

    const float4* xg = (const float4*)x;
    const long b0 = (long)row0 * 512 + s * 128 + hs;   // float4 units
    const long b1 = b0 + 512;

    // hoist all x loads (16 dwordx4 in flight per lane)
    float4 xa[8], xb[8];
    #pragma unroll
    for (int c = 0; c < 8; ++c) {
        xa[c] = xg[b0 + c * 16];
        xb[c] = xg[b1 + c * 16];
    }

    float acc0[13], acc1[13];
    #pragma unroll
    for (int j = 0; j < 13; ++j) { acc0[j] = 0.f; acc1[j] = 0.f; }

    const h4_t* w4 = (const h4_t*)wl;   // h4 idx = j*128 + c*16 + hs

    #pragma unroll
    for (int c = 0; c < 8; ++c) {
        const h2_t xl0 = __builtin_amdgcn_cvt_pkrtz(xa[c].x, xa[c].y);
        const h2_t xh0 = __builtin_amdgcn_cvt_pkrtz(xa[c].z, xa[c].w);
        const h2_t xl1 = __builtin_amdgcn_cvt_pkrtz(xb[c].x, xb[c].y);
        const h2_t xh1 = __builtin_amdgcn_cvt_pkrtz(xb[c].z, xb[c].w);
        const int wb = c * 16 + hs;
        #pragma unroll
        for (int j = 0; j < 13; ++j) {
            const h4_t wv = w4[j * 128 + wb];
            const h2_t wlo = __builtin_shufflevector(wv, wv, 0, 1);
            const h2_t whi = __builtin_shufflevector(wv, wv, 2, 3);
#if __has_builtin(__builtin_amdgcn_fdot2)
            acc0[j] = __builtin_amdgcn_fdot2(xl0, wlo, acc0[j], false);
            acc0[j] = __builtin_amdgcn_fdot2(xh0, whi, acc0[j], false);
            acc1[j] = __builtin_amdgcn_fdot2(xl1, wlo, acc1[j], false);
            acc1[j] = __builtin_amdgcn_fdot2(xh1, whi, acc1[j], false);
#else
            acc0[j] += (float)xl0.x * (float)wlo.x + (float)xl0.y * (float)wlo.y
                     + (float)xh0.x * (float)whi.x + (float)xh0.y * (float)whi.y;
            acc1[j] += (float)xl1.x * (float)wlo.x + (float)xl1.y * (float)wlo.y
                     + (float)xh1.x * (float)whi.x + (float)xh1.y * (float)whi.y;
#endif
        }
    }

    #pragma unroll
    for (int j = 0; j < 13; ++j) {
        acc0[j] += __shfl_xor(acc0[j], 1, 64);
        acc0[j] += __shfl_xor(acc0[j], 2, 64);
        acc0[j] += __shfl_xor(acc0[j], 4, 64);
        acc0[j] += __shfl_xor(acc0[j], 8, 64);
        acc1[j] += __shfl_xor(acc1[j], 1, 64);
        acc1[j] += __shfl_xor(acc1[j], 2, 64);
        acc1[j] += __shfl_xor(acc1[j], 4, 64);
        acc1[j] += __shfl_xor(acc1[j], 8, 64);
    }

    // lane hs writes column j=hs of its row pair (cndmask select chain)
    float v0 = acc0[12], v1 = acc1[12];
    #pragma unroll
    for (int j = 11; j >= 0; --j) {
        v0 = (hs == j) ? acc0[j] : v0;
        v1 = (hs == j) ? acc1[j] : v1;
    }
    if (hs < 13) {
        const long pbase = ((long)(s << 14) + row0) * 13;
        part[pbase + hs]      = v0;
        part[pbase + 13 + hs] = v1;
    }
}

__global__ __launch_bounds__(256)
void reduce_epilogue(const float* __restrict__ part,
                     const float* __restrict__ bg, const float* __restrict__ bp,
                     const float* __restrict__ ba, float* __restrict__ out)
{
    const int r = blockIdx.x * 256 + threadIdx.x;   // row

    float acc[13];
    #pragma unroll
    for (int j = 0; j < 13; ++j) acc[j] = 0.f;
    #pragma unroll
    for (int s = 0; s < 4; ++s) {
        const long pbase = ((long)(s << 14) + r) * 13;
        #pragma unroll
        for (int j = 0; j < 13; ++j) acc[j] += part[pbase + j];
    }

    const float g0 = acc[0] + bg[0], g1 = acc[1] + bg[1], g2 = acc[2] + bg[2], g3 = acc[3] + bg[3];
    const float q0 = acc[4] + bp[0], q1 = acc[5] + bp[1], q2 = acc[6] + bp[2], q3 = acc[7] + bp[3];
    const float a0 = acc[8] + ba[0], a1 = acc[9] + ba[1], a2 = acc[10] + ba[2],
                a3 = acc[11] + ba[3], a4 = acc[12] + ba[4];

    float m, sum, inv;
    m = fmaxf(fmaxf(g0, g1), fmaxf(g2, g3));
    const float eg0 = __expf(g0 - m), eg1 = __expf(g1 - m), eg2 = __expf(g2 - m), eg3 = __expf(g3 - m);
    sum = eg0 + eg1 + eg2 + eg3; inv = 1.f / sum;
    const float G0 = eg0 * inv, G1 = eg1 * inv, G2 = eg2 * inv, G3 = eg3 * inv;

    m = fmaxf(fmaxf(q0, q1), fmaxf(q2, q3));
    const float ep0 = __expf(q0 - m), ep1 = __expf(q1 - m), ep2 = __expf(q2 - m), ep3 = __expf(q3 - m);
    sum = ep0 + ep1 + ep2 + ep3; inv = 1.f / sum;
    const float P0 = ep0 * inv, P1 = ep1 * inv, P2 = ep2 * inv, P3 = ep3 * inv;

    m = fmaxf(fmaxf(fmaxf(a0, a1), fmaxf(a2, a3)), a4);
    const float ea0 = __expf(a0 - m), ea1 = __expf(a1 - m), ea2 = __expf(a2 - m),
                ea3 = __expf(a3 - m), ea4 = __expf(a4 - m);
    sum = ea0 + ea1 + ea2 + ea3 + ea4; inv = 1.f / sum;
    const float A0 = ea0 * inv, A1 = ea1 * inv, A2 = ea2 * inv, A3 = ea3 * inv, A4 = ea4 * inv;

    const float u0 = P0 * G0 + P1 * G1 + P2 * G2 + P3 * G3;
    const float u1 = P0 * G1 + P2 * G3;
    const float u2 = P1 * G0 + P3 * G2;

    const float j0 = A0 * (1.f - u0), j1 = A1 * (1.f - u1), j2 = A2 * (1.f - u2),
                j3 = A3, j4 = A4;
    const float isd = 1.f / (j0 + j1 + j2 + j3 + j4);

    float* o = out + (long)r * 5;
    o[0] = j0 * isd; o[1] = j1 * isd; o[2] = j2 * isd; o[3] = j3 * isd; o[4] = j4 * isd;
}

extern "C" void kernel_launch(void* const* d_in, const int* in_sizes, int n_in,
                              void* d_out, int out_size, void* d_ws, size_t ws_size,
                              hipStream_t stream) {
    const float* x  = (const float*)d_in[0];
    const float* Wg = (const float*)d_in[1];
    const float* bg = (const float*)d_in[2];
    const float* Wp = (const float*)d_in[3];
    const float* bp = (const float*)d_in[4];
    const float* Wa = (const float*)d_in[5];
    const float* ba = (const float*)d_in[6];
    float* out = (float*)d_out;

    __fp16* wpk = (__fp16*)d_ws;
    float* part = (float*)((char*)d_ws + WS_PART_OFF);

    pack_weights<<<104, 256, 0, stream>>>(Wg, Wp, Wa, wpk);
    gemm_partial<<<2048, 256, 0, stream>>>(x, wpk, part);
    reduce_epilogue<<<64, 256, 0, stream>>>(part, bg, bp, ba, out);
}